// Round 1
// baseline (287.078 us; speedup 1.0000x reference)
//
#include <hip/hip_runtime.h>
#include <hip/hip_bf16.h>
#include <math.h>

#define N_PTS 32768
#define IN_F  256
#define NUM_CAT 16
#define CF    4096
#define NSEG  6
#define OUTK  50
#define BN_EPS 1e-5f

// ---- ws layout (float offsets) ----
// Gram partials: 8 tiles(2a x 4b: 128x64) x 32 K-chunks x 128x64
#define OFF_GP    0u                 // 8*32*8192 = 2,097,152 floats (8 MB)
#define OFF_CS    2097152u           // colsum partials: 32*256
#define OFF_G     2105344u           // 256*256
#define OFF_FBAR  2170880u           // 256
#define OFF_SCALE 2171136u           // 4096
#define OFF_SHIFT 2175232u           // 4096
#define OFF_INT   2179328u           // int region below
// int offsets (relative, in ints)
#define IO_COUNTS 0
#define IO_CATOFF 16
#define IO_TILEST 33
#define IO_NTILES 50
#define IO_CURSOR 51
#define IO_ORDER  67                 // 32768 ints
// total ws need: (2179328 + 67 + 32768)*4 B ~= 8.85 MB

// ============ K1: Gram partials (split-K) + column-sum partials ============
__global__ __launch_bounds__(256) void k1_gram(const float* __restrict__ F,
                                               float* __restrict__ ws) {
    const int tile  = blockIdx.x & 7;    // 8 tiles: ta(0..1)x128, tb(0..3)x64
    const int chunk = blockIdx.x >> 3;   // 32 K-chunks of 1024 rows
    const int ta = tile >> 2, tb = tile & 3;
    const int a0 = ta * 128, b0 = tb * 64;
    const int r0 = chunk * 1024;
    const int tid = threadIdx.x;
    __shared__ __align__(16) float Alds[32][128];
    __shared__ __align__(16) float Blds[32][64];
    float acc[4][8];
#pragma unroll
    for (int i = 0; i < 4; i++)
#pragma unroll
        for (int j = 0; j < 8; j++) acc[i][j] = 0.f;
    float colacc = 0.f;
    const int tx = tid & 31, ty = tid >> 5;   // a-group(32x4), b-group(8x8)

    for (int k0 = 0; k0 < 1024; k0 += 32) {
        __syncthreads();
#pragma unroll
        for (int i = 0; i < 4; i++) {        // A: 32 rows x 128 cols
            int slot = tid + i * 256;
            int kk = slot >> 5, seg = slot & 31;
            float4 v = *(const float4*)&F[(size_t)(r0 + k0 + kk) * IN_F + a0 + seg * 4];
            *(float4*)&Alds[kk][seg * 4] = v;
        }
#pragma unroll
        for (int i = 0; i < 2; i++) {        // B: 32 rows x 64 cols
            int slot = tid + i * 256;
            int kk = slot >> 4, seg = slot & 15;
            float4 v = *(const float4*)&F[(size_t)(r0 + k0 + kk) * IN_F + b0 + seg * 4];
            *(float4*)&Blds[kk][seg * 4] = v;
        }
        __syncthreads();
#pragma unroll 8
        for (int kk = 0; kk < 32; kk++) {
            float4 av  = *(const float4*)&Alds[kk][tx * 4];
            float4 bv0 = *(const float4*)&Blds[kk][ty * 8];
            float4 bv1 = *(const float4*)&Blds[kk][ty * 8 + 4];
            float a_[4] = {av.x, av.y, av.z, av.w};
            float b_[8] = {bv0.x, bv0.y, bv0.z, bv0.w, bv1.x, bv1.y, bv1.z, bv1.w};
#pragma unroll
            for (int i = 0; i < 4; i++)
#pragma unroll
                for (int j = 0; j < 8; j++) acc[i][j] += a_[i] * b_[j];
        }
        if (tb == 0 && tid < 128) {          // fold column-sum into diagonal-col tiles
#pragma unroll 8
            for (int kk = 0; kk < 32; kk++) colacc += Alds[kk][tid];
        }
    }
    float* Gp = ws + OFF_GP + (size_t)(tile * 32 + chunk) * 8192;
#pragma unroll
    for (int i = 0; i < 4; i++)
#pragma unroll
        for (int j = 0; j < 8; j++)
            Gp[(tx * 4 + i) * 64 + ty * 8 + j] = acc[i][j];
    if (tb == 0 && tid < 128) ws[OFF_CS + chunk * 256 + a0 + tid] = colacc;
}

// ============ K2a: reduce partials -> G, colsums -> fbar; zero counts ============
__global__ __launch_bounds__(256) void k2a_reduce(float* __restrict__ ws) {
    const int tid = threadIdx.x;
    const int e = blockIdx.x * 256 + tid;      // 0..65535
    const int a = e >> 8, b = e & 255;
    const int tile = (a >> 7) * 4 + (b >> 6);
    const int al = a & 127, bl = b & 63;
    const float* Gp = ws + OFF_GP;
    float s = 0.f;
#pragma unroll 8
    for (int c = 0; c < 32; c++)
        s += Gp[(size_t)(tile * 32 + c) * 8192 + al * 64 + bl];
    ws[OFF_G + e] = s;
    if (blockIdx.x == 0) {
        float fs = 0.f;
#pragma unroll 8
        for (int c = 0; c < 32; c++) fs += ws[OFF_CS + c * 256 + tid];
        ws[OFF_FBAR + tid] = fs * (1.0f / N_PTS);
        int* wi = (int*)(ws + OFF_INT);
        if (tid < 16) wi[IO_COUNTS + tid] = 0;
    }
}

// ============ K2b: per-column mu/var -> scale/shift ============
__global__ __launch_bounds__(256) void k2b_stats(const float* __restrict__ W1,
                                                 const float* __restrict__ gamma,
                                                 const float* __restrict__ beta,
                                                 float* __restrict__ ws) {
    const int tid = threadIdx.x;
    const int j0 = blockIdx.x * 16;
    __shared__ __align__(16) float wl[16][256];
    __shared__ float pw[16][8];
#pragma unroll
    for (int q = 0; q < 4; q++) {
        float4 v = *(const float4*)&W1[(size_t)tid * CF + j0 + q * 4];
        wl[q * 4 + 0][tid] = v.x; wl[q * 4 + 1][tid] = v.y;
        wl[q * 4 + 2][tid] = v.z; wl[q * 4 + 3][tid] = v.w;
    }
    __syncthreads();
    float acc[16];
#pragma unroll
    for (int jj = 0; jj < 16; jj++) acc[jj] = 0.f;
    const float* G = ws + OFF_G;
    for (int b = 0; b < 256; b++) {           // s_a = sum_b G[b][a] * w[jj][b]
        float g = G[b * 256 + tid];
#pragma unroll
        for (int jj = 0; jj < 16; jj++) acc[jj] += g * wl[jj][b];
    }
    float fb = ws[OFF_FBAR + tid];
    const int lane = tid & 63, wave = tid >> 6;
#pragma unroll
    for (int jj = 0; jj < 16; jj++) {
        float w = wl[jj][tid];
        float v = w * acc[jj];                // -> sum_a w_a s_a = w^T G w
        float m = fb * w;                     // -> mu = fbar . w
#pragma unroll
        for (int off = 32; off >= 1; off >>= 1) {
            v += __shfl_xor(v, off);
            m += __shfl_xor(m, off);
        }
        if (lane == 0) { pw[jj][wave * 2] = v; pw[jj][wave * 2 + 1] = m; }
    }
    __syncthreads();
    if (tid < 16) {
        int jj = tid;
        float v = 0.f, m = 0.f;
        for (int w2 = 0; w2 < 4; w2++) { v += pw[jj][w2 * 2]; m += pw[jj][w2 * 2 + 1]; }
        float mu  = m;
        float var = v * (1.0f / N_PTS) - mu * mu;
        float sc  = gamma[j0 + jj] * rsqrtf(var + BN_EPS);
        float sh  = beta[j0 + jj] - mu * sc;
        ws[OFF_SCALE + j0 + jj] = sc;
        ws[OFF_SHIFT + j0 + jj] = sh;
    }
}

// ============ K3: category histogram ============
__global__ __launch_bounds__(256) void k3_hist(const int* __restrict__ cats,
                                               float* __restrict__ ws) {
    __shared__ int h[16];
    int tid = threadIdx.x;
    if (tid < 16) h[tid] = 0;
    __syncthreads();
    for (int n = blockIdx.x * 256 + tid; n < N_PTS; n += 64 * 256)
        atomicAdd(&h[cats[n]], 1);
    __syncthreads();
    int* wi = (int*)(ws + OFF_INT);
    if (tid < 16) atomicAdd(&wi[IO_COUNTS + tid], h[tid]);
}

// ============ K4: prefix sums (serial, tiny) ============
__global__ void k4_prefix(float* __restrict__ ws) {
    int* wi = (int*)(ws + OFF_INT);
    if (threadIdx.x == 0) {
        int co = 0, ts = 0;
        wi[IO_CATOFF] = 0; wi[IO_TILEST] = 0;
        for (int c = 0; c < 16; c++) {
            int cnt = wi[IO_COUNTS + c];
            wi[IO_CURSOR + c] = co;
            co += cnt; ts += (cnt + 63) >> 6;
            wi[IO_CATOFF + c + 1] = co;
            wi[IO_TILEST + c + 1] = ts;
        }
        wi[IO_NTILES] = ts;
    }
}

// ============ K4b: scatter point ids grouped by category ============
__global__ __launch_bounds__(256) void k4b_scatter(const int* __restrict__ cats,
                                                   float* __restrict__ ws) {
    int* wi = (int*)(ws + OFF_INT);
    for (int n = blockIdx.x * 256 + threadIdx.x; n < N_PTS; n += 64 * 256) {
        int c = cats[n];
        int idx = atomicAdd(&wi[IO_CURSOR + c], 1);
        wi[IO_ORDER + idx] = n;
    }
}

// ============ K5: per-category GEMM + BN + LeakyReLU + Wc + log_softmax + scatter ============
__global__ __launch_bounds__(256) void k5_main(const float* __restrict__ F,
                                               const float* __restrict__ W1,
                                               const float* __restrict__ Wc,
                                               const float* __restrict__ bias,
                                               const int* __restrict__ shifts,
                                               const int* __restrict__ seg_lens,
                                               const float* __restrict__ ws,
                                               float* __restrict__ out) {
    const int* wi = (const int*)(ws + OFF_INT);
    const int t = blockIdx.x;
    if (t >= wi[IO_NTILES]) return;
    int c = 0;
    while (!(t >= wi[IO_TILEST + c] && t < wi[IO_TILEST + c + 1])) c++;
    const int lt = t - wi[IO_TILEST + c];
    const int base = wi[IO_CATOFF + c] + lt * 64;
    const int npts = min(64, wi[IO_COUNTS + c] - lt * 64);
    const int tid = threadIdx.x;

    __shared__ __align__(16) float Wlds[32][256];   // reused as red[16][64][6] in epilogue
    __shared__ __align__(16) float Flds[32][68];
    __shared__ float scl[256], shl[256];
    __shared__ float wcl[256 * 6];
    __shared__ int plds[64];

    if (tid < 64) plds[tid] = wi[IO_ORDER + base + min(tid, npts - 1)];
    scl[tid] = ws[OFF_SCALE + c * 256 + tid];
    shl[tid] = ws[OFF_SHIFT + c * 256 + tid];
#pragma unroll
    for (int i = 0; i < 6; i++) {
        int idx = tid + i * 256;
        wcl[idx] = Wc[(size_t)c * 1536 + idx];
    }
    __syncthreads();

    const int tm = tid & 15, tn = tid >> 4;   // 4 pts x 16 cols per thread
    float acc[4][16];
#pragma unroll
    for (int i = 0; i < 4; i++)
#pragma unroll
        for (int j = 0; j < 16; j++) acc[i][j] = 0.f;

    for (int k0 = 0; k0 < 256; k0 += 32) {
        {   // gathered feature rows, transposed into LDS
            int m = tid >> 2, seg = tid & 3;
            const float* src = &F[(size_t)plds[m] * IN_F + k0 + seg * 8];
            float4 v0 = *(const float4*)src;
            float4 v1 = *(const float4*)(src + 4);
            Flds[seg * 8 + 0][m] = v0.x; Flds[seg * 8 + 1][m] = v0.y;
            Flds[seg * 8 + 2][m] = v0.z; Flds[seg * 8 + 3][m] = v0.w;
            Flds[seg * 8 + 4][m] = v1.x; Flds[seg * 8 + 5][m] = v1.y;
            Flds[seg * 8 + 6][m] = v1.z; Flds[seg * 8 + 7][m] = v1.w;
        }
#pragma unroll
        for (int i = 0; i < 8; i++) {             // W1 category block chunk
            int slot = i * 256 + tid;
            int kk = slot >> 6, seg = slot & 63;
            *(float4*)&Wlds[kk][seg * 4] =
                *(const float4*)&W1[(size_t)(k0 + kk) * CF + c * 256 + seg * 4];
        }
        __syncthreads();
#pragma unroll 4
        for (int kk = 0; kk < 32; kk++) {
            float4 f4 = *(const float4*)&Flds[kk][tm * 4];
            float f_[4] = {f4.x, f4.y, f4.z, f4.w};
#pragma unroll
            for (int q = 0; q < 4; q++) {
                float4 w4 = *(const float4*)&Wlds[kk][tn * 16 + q * 4];
                float w_[4] = {w4.x, w4.y, w4.z, w4.w};
#pragma unroll
                for (int i = 0; i < 4; i++)
#pragma unroll
                    for (int u = 0; u < 4; u++)
                        acc[i][q * 4 + u] += f_[i] * w_[u];
            }
        }
        __syncthreads();
    }

    // epilogue: BN + LeakyReLU + partial logits vs Wc
    float pl[4][6];
#pragma unroll
    for (int i = 0; i < 4; i++)
#pragma unroll
        for (int s = 0; s < 6; s++) pl[i][s] = 0.f;
#pragma unroll
    for (int j = 0; j < 16; j++) {
        int n = tn * 16 + j;
        float sc = scl[n], sh = shl[n];
#pragma unroll
        for (int i = 0; i < 4; i++) {
            float x = acc[i][j] * sc + sh;
            x = (x >= 0.f) ? x : 0.2f * x;
#pragma unroll
            for (int s = 0; s < 6; s++) pl[i][s] += x * wcl[n * 6 + s];
        }
    }
    float* red = &Wlds[0][0];                 // 16*64*6 = 6144 floats, fits
#pragma unroll
    for (int i = 0; i < 4; i++)
#pragma unroll
        for (int s = 0; s < 6; s++)
            red[(tn * 64 + tm * 4 + i) * 6 + s] = pl[i][s];
    __syncthreads();

    if (tid < 64 && tid < npts) {
        const int m = tid;
        float lg[6];
#pragma unroll
        for (int s = 0; s < 6; s++) lg[s] = bias[s];
        for (int w = 0; w < 16; w++)
#pragma unroll
            for (int s = 0; s < 6; s++) lg[s] += red[(w * 64 + m) * 6 + s];
        float mx = lg[0];
#pragma unroll
        for (int s = 1; s < 6; s++) mx = fmaxf(mx, lg[s]);
        float se = 0.f;
#pragma unroll
        for (int s = 0; s < 6; s++) se += expf(lg[s] - mx);
        float lse = mx + logf(se);
        const int pid = plds[m];
        const int sh = shifts[c], ln = seg_lens[c];
        float* orow = out + (size_t)pid * OUTK;
        for (int k = 0; k < OUTK; k++) {
            int j = k - sh;
            orow[k] = (j >= 0 && j < ln) ? (lg[j] - lse) : 0.f;
        }
    }
}

extern "C" void kernel_launch(void* const* d_in, const int* in_sizes, int n_in,
                              void* d_out, int out_size, void* d_ws, size_t ws_size,
                              hipStream_t stream) {
    const float* F      = (const float*)d_in[0];
    const float* W1     = (const float*)d_in[1];
    const float* gamma  = (const float*)d_in[2];
    const float* beta   = (const float*)d_in[3];
    const float* Wc     = (const float*)d_in[4];
    const float* bias   = (const float*)d_in[5];
    const int*  cats    = (const int*)d_in[6];
    const int*  shifts  = (const int*)d_in[7];
    const int*  seglens = (const int*)d_in[8];
    float* out = (float*)d_out;
    float* ws  = (float*)d_ws;

    hipLaunchKernelGGL(k1_gram,     dim3(256), dim3(256), 0, stream, F, ws);
    hipLaunchKernelGGL(k2a_reduce,  dim3(256), dim3(256), 0, stream, ws);
    hipLaunchKernelGGL(k2b_stats,   dim3(256), dim3(256), 0, stream, W1, gamma, beta, ws);
    hipLaunchKernelGGL(k3_hist,     dim3(64),  dim3(256), 0, stream, cats, ws);
    hipLaunchKernelGGL(k4_prefix,   dim3(1),   dim3(64),  0, stream, ws);
    hipLaunchKernelGGL(k4b_scatter, dim3(64),  dim3(256), 0, stream, cats, ws);
    hipLaunchKernelGGL(k5_main,     dim3(528), dim3(256), 0, stream,
                       F, W1, Wc, bias, shifts, seglens, ws, out);
}